// Round 2
// baseline (329.925 us; speedup 1.0000x reference)
//
#include <hip/hip_runtime.h>
#include <hip/hip_bf16.h>

#define TEXT_N 226
#define D_N    1024
#define HEADS_N 16
#define HD_N   64
#define ST_N   1248
#define S_N    1474        // TEXT+ST
#define L0_N   2722        // S+ST (cond key length)
#define L0P_N  2752        // padded to 43*64
#define SP_N   1536        // padded S (24*64)
#define M_ROWS 2948        // 2*S
#define NEGB   -1000000000.0f

typedef __hip_bfloat16 bf16_t;
typedef short s16x8 __attribute__((ext_vector_type(8)));   // 8 bf16 (4 VGPRs)
typedef float f32x4 __attribute__((ext_vector_type(4)));

__device__ __forceinline__ f32x4 mfma16(s16x8 a, s16x8 b, f32x4 c) {
    return __builtin_amdgcn_mfma_f32_16x16x32_bf16(a, b, c, 0, 0, 0);
}

__device__ __forceinline__ short f2bs(float x) {
    __hip_bfloat16 h = __float2bfloat16(x);
    return *(short*)&h;
}

// ---------------- weight transpose + fp32->bf16: wt[n][k] = bf16(w[k][n]) ----------------
__global__ __launch_bounds__(256) void transpose_k(
    const float* __restrict__ w0, const float* __restrict__ w1,
    const float* __restrict__ w2, const float* __restrict__ w3,
    bf16_t* __restrict__ o0, bf16_t* __restrict__ o1,
    bf16_t* __restrict__ o2, bf16_t* __restrict__ o3) {
    __shared__ bf16_t t[32][33];
    const float* src; bf16_t* dst;
    switch (blockIdx.z) {
        case 0: src = w0; dst = o0; break;
        case 1: src = w1; dst = o1; break;
        case 2: src = w2; dst = o2; break;
        default: src = w3; dst = o3; break;
    }
    int bx = blockIdx.x * 32, by = blockIdx.y * 32;
    int tx = threadIdx.x, ty = threadIdx.y;              // block (32,8)
    for (int i = ty; i < 32; i += 8)
        t[i][tx] = __float2bfloat16(src[(size_t)(by + i) * D_N + bx + tx]);
    __syncthreads();
    for (int i = ty; i < 32; i += 8)
        dst[(size_t)(bx + i) * D_N + by + tx] = t[tx][i];
}

// ---------------- fused QKV projection GEMM ----------------
// A = fp32 x (concat[enc,hid]) rows m=(b,s), converted to bf16 at staging;
// B = wt (bf16, n-major); z selects Q/K/V.
__global__ __launch_bounds__(256) void qkv_proj(
    const float* __restrict__ enc, const float* __restrict__ hid,
    const bf16_t* __restrict__ wtq, const bf16_t* __restrict__ wtk, const bf16_t* __restrict__ wtv,
    const float* __restrict__ bq, const float* __restrict__ bk, const float* __restrict__ bv,
    bf16_t* __restrict__ Q, bf16_t* __restrict__ Kc, bf16_t* __restrict__ Ku,
    bf16_t* __restrict__ Vct, bf16_t* __restrict__ Vut) {
    __shared__ __align__(16) bf16_t As[128 * 32];
    __shared__ __align__(16) bf16_t Bs[128 * 32];
    const int z = blockIdx.z;
    const bf16_t* wt   = (z == 0) ? wtq : (z == 1) ? wtk : wtv;
    const float*  bias = (z == 0) ? bq  : (z == 1) ? bk  : bv;
    const int n0 = blockIdx.x * 128, m0 = blockIdx.y * 128;
    const int t = threadIdx.x;
    const int wave = t >> 6, lane = t & 63, ln = lane & 15, qd = lane >> 4;
    const int wm = (wave >> 1) * 64, wn = (wave & 1) * 64;

    f32x4 acc[4][4];
    const f32x4 z4 = {0.f, 0.f, 0.f, 0.f};
#pragma unroll
    for (int mi = 0; mi < 4; mi++)
#pragma unroll
        for (int ni = 0; ni < 4; ni++) acc[mi][ni] = z4;
    const s16x8 zero8 = {0, 0, 0, 0, 0, 0, 0, 0};

    for (int k0 = 0; k0 < D_N; k0 += 32) {
#pragma unroll
        for (int c = t; c < 512; c += 256) {
            int row = c >> 2, cc = (c & 3) << 3;
            int m = m0 + row;
            s16x8 av = zero8;
            if (m < M_ROWS) {
                int b = m >= S_N; int s = m - b * S_N;
                const float* src = (s < TEXT_N)
                    ? (enc + (size_t)(b * TEXT_N + s) * D_N)
                    : (hid + (size_t)(b * ST_N + (s - TEXT_N)) * D_N);
                const float4 f0 = *(const float4*)(src + k0 + cc);
                const float4 f1 = *(const float4*)(src + k0 + cc + 4);
                av[0] = f2bs(f0.x); av[1] = f2bs(f0.y); av[2] = f2bs(f0.z); av[3] = f2bs(f0.w);
                av[4] = f2bs(f1.x); av[5] = f2bs(f1.y); av[6] = f2bs(f1.z); av[7] = f2bs(f1.w);
            }
            *(s16x8*)(As + row * 32 + cc) = av;
            int n = n0 + row;
            *(s16x8*)(Bs + row * 32 + cc) = *(const s16x8*)(wt + (size_t)n * D_N + k0 + cc);
        }
        __syncthreads();
        s16x8 af[4], bfr[4];
#pragma unroll
        for (int mi = 0; mi < 4; mi++) af[mi]  = *(const s16x8*)(As + (wm + mi * 16 + ln) * 32 + qd * 8);
#pragma unroll
        for (int ni = 0; ni < 4; ni++) bfr[ni] = *(const s16x8*)(Bs + (wn + ni * 16 + ln) * 32 + qd * 8);
#pragma unroll
        for (int mi = 0; mi < 4; mi++)
#pragma unroll
            for (int ni = 0; ni < 4; ni++) acc[mi][ni] = mfma16(af[mi], bfr[ni], acc[mi][ni]);
        __syncthreads();
    }

    // epilogue: scatter into attention layouts
#pragma unroll
    for (int ni = 0; ni < 4; ni++) {
        int n = n0 + wn + ni * 16 + ln;
        float bn = bias[n];
        int h = n >> 6, d = n & 63;
#pragma unroll
        for (int mi = 0; mi < 4; mi++) {
#pragma unroll
            for (int r = 0; r < 4; r++) {
                int m = m0 + wm + mi * 16 + qd * 4 + r;
                if (m >= M_ROWS) continue;
                int b = m >= S_N; int s = m - b * S_N;
                bf16_t v = __float2bfloat16(acc[mi][ni][r] + bn);
                if (z == 0) {
                    Q[((size_t)(b * HEADS_N + h) * SP_N + s) * HD_N + d] = v;
                } else if (z == 1) {
                    if (!b) {
                        Kc[((size_t)h * L0P_N + s) * HD_N + d] = v;
                    } else {
                        Ku[((size_t)h * SP_N + s) * HD_N + d] = v;
                        if (s >= TEXT_N) Kc[((size_t)h * L0P_N + (S_N + s - TEXT_N)) * HD_N + d] = v;
                    }
                } else {
                    if (!b) {
                        Vct[(size_t)(h * HD_N + d) * L0P_N + s] = v;
                    } else {
                        Vut[(size_t)(h * HD_N + d) * SP_N + s] = v;
                        if (s >= TEXT_N) Vct[(size_t)(h * HD_N + d) * L0P_N + (S_N + s - TEXT_N)] = v;
                    }
                }
            }
        }
    }
}

// ---------------- flash attention ----------------
// grid (24 q-tiles, 16 heads, 2 cases). case0 = cond(b=0,q) vs concat KV + bias; case1 = uncond(b=1).
__global__ __launch_bounds__(256) void attn_k(
    const bf16_t* __restrict__ Q, const bf16_t* __restrict__ Kc, const bf16_t* __restrict__ Ku,
    const bf16_t* __restrict__ Vct, const bf16_t* __restrict__ Vut,
    const int* __restrict__ mask, bf16_t* __restrict__ hs) {
    __shared__ __align__(16) bf16_t Ks[64 * 64];       // [j][d]
    __shared__ __align__(16) bf16_t Vs[64 * 64];       // [d][j]
    __shared__ __align__(16) bf16_t Ps[4][16 * 64];    // per-wave P tile [q][j]
    const int cs = blockIdx.z, h = blockIdx.y, q0 = blockIdx.x * 64;
    const int L  = cs ? S_N : L0_N;
    const int nt = cs ? (SP_N / 64) : (L0P_N / 64);    // 24 or 43
    const bf16_t* Kp = cs ? (Ku + (size_t)h * SP_N * HD_N) : (Kc + (size_t)h * L0P_N * HD_N);
    const bf16_t* Vp = cs ? (Vut + (size_t)h * HD_N * SP_N) : (Vct + (size_t)h * HD_N * L0P_N);
    const int vstr = cs ? SP_N : L0P_N;
    const bf16_t* Qp = Q + (size_t)(cs * HEADS_N + h) * SP_N * HD_N;
    const int t = threadIdx.x, wave = t >> 6, lane = t & 63, ln = lane & 15, qd = lane >> 4;

    s16x8 qf[2];
#pragma unroll
    for (int kk = 0; kk < 2; kk++)
        qf[kk] = *(const s16x8*)(Qp + (size_t)(q0 + wave * 16 + ln) * HD_N + kk * 32 + qd * 8);

    f32x4 o[4];
    const f32x4 z4 = {0.f, 0.f, 0.f, 0.f};
#pragma unroll
    for (int ni = 0; ni < 4; ni++) o[ni] = z4;
    float m_r[4], l_r[4];
#pragma unroll
    for (int r = 0; r < 4; r++) { m_r[r] = -1e30f; l_r[r] = 0.f; }

    for (int kt = 0; kt < nt; kt++) {
        const int j0 = kt * 64;
#pragma unroll
        for (int c = t; c < 512; c += 256) {
            int row = c >> 3, cc = (c & 7) << 3;
            *(s16x8*)(Ks + row * 64 + cc) = *(const s16x8*)(Kp + (size_t)(j0 + row) * HD_N + cc);
            *(s16x8*)(Vs + row * 64 + cc) = *(const s16x8*)(Vp + (size_t)row * vstr + j0 + cc);
        }
        __syncthreads();

        // S = Q K^T
        f32x4 sc[4];
#pragma unroll
        for (int ni = 0; ni < 4; ni++) sc[ni] = z4;
#pragma unroll
        for (int kk = 0; kk < 2; kk++) {
#pragma unroll
            for (int ni = 0; ni < 4; ni++) {
                s16x8 kb = *(const s16x8*)(Ks + (ni * 16 + ln) * 64 + kk * 32 + qd * 8);
                sc[ni] = mfma16(qf[kk], kb, sc[ni]);
            }
        }
        // scale + bias + OOB mask (col j = j0 + ni*16 + ln, same for all 4 rows)
#pragma unroll
        for (int ni = 0; ni < 4; ni++) {
            int j = j0 + ni * 16 + ln;
            float badd = 0.f;
            bool valid = j < L;
            if (!cs && valid && j >= S_N) badd = (mask[j - S_N] > 0) ? 0.f : NEGB;
#pragma unroll
            for (int r = 0; r < 4; r++)
                sc[ni][r] = valid ? (sc[ni][r] * 0.125f + badd) : -1e30f;
        }
        // online softmax (rows = qd*4+r, cols across ln within quad)
        float alpha[4], rs[4];
#pragma unroll
        for (int r = 0; r < 4; r++) {
            float v = fmaxf(fmaxf(sc[0][r], sc[1][r]), fmaxf(sc[2][r], sc[3][r]));
#pragma unroll
            for (int off = 1; off < 16; off <<= 1) v = fmaxf(v, __shfl_xor(v, off));
            float mn = fmaxf(m_r[r], v);
            alpha[r] = __expf(m_r[r] - mn);
            m_r[r] = mn;
            rs[r] = 0.f;
        }
#pragma unroll
        for (int ni = 0; ni < 4; ni++)
#pragma unroll
            for (int r = 0; r < 4; r++) {
                float p = __expf(sc[ni][r] - m_r[r]);
                sc[ni][r] = p;
                rs[r] += p;
            }
#pragma unroll
        for (int r = 0; r < 4; r++) {
#pragma unroll
            for (int off = 1; off < 16; off <<= 1) rs[r] += __shfl_xor(rs[r], off);
            l_r[r] = l_r[r] * alpha[r] + rs[r];
        }
        // P -> LDS (C-layout write), rescale O
#pragma unroll
        for (int ni = 0; ni < 4; ni++) {
#pragma unroll
            for (int r = 0; r < 4; r++)
                Ps[wave][(qd * 4 + r) * 64 + ni * 16 + ln] = __float2bfloat16(sc[ni][r]);
            o[ni][0] *= alpha[0]; o[ni][1] *= alpha[1]; o[ni][2] *= alpha[2]; o[ni][3] *= alpha[3];
        }
        asm volatile("s_waitcnt lgkmcnt(0)" ::: "memory");  // order per-wave LDS write->read
        // O += P V  (P as A-frag from LDS, V n-major)
#pragma unroll
        for (int kk = 0; kk < 2; kk++) {
            s16x8 pa = *(const s16x8*)(&Ps[wave][ln * 64 + kk * 32 + qd * 8]);
#pragma unroll
            for (int ni = 0; ni < 4; ni++) {
                s16x8 vb = *(const s16x8*)(Vs + (ni * 16 + ln) * 64 + kk * 32 + qd * 8);
                o[ni] = mfma16(pa, vb, o[ni]);
            }
        }
        __syncthreads();
    }
    // normalize + store hs[b][s][h*64+d]
#pragma unroll
    for (int ni = 0; ni < 4; ni++) {
#pragma unroll
        for (int r = 0; r < 4; r++) {
            int q = q0 + wave * 16 + qd * 4 + r;
            if (q < S_N) {
                float v = o[ni][r] / l_r[r];
                hs[(size_t)(cs * S_N + q) * D_N + h * HD_N + ni * 16 + ln] = __float2bfloat16(v);
            }
        }
    }
}

// ---------------- output projection GEMM + split fp32 store ----------------
__global__ __launch_bounds__(256) void out_proj(
    const bf16_t* __restrict__ hsp, const bf16_t* __restrict__ wto,
    const float* __restrict__ bo, float* __restrict__ out) {
    __shared__ __align__(16) bf16_t As[128 * 32];
    __shared__ __align__(16) bf16_t Bs[128 * 32];
    const int n0 = blockIdx.x * 128, m0 = blockIdx.y * 128;
    const int t = threadIdx.x;
    const int wave = t >> 6, lane = t & 63, ln = lane & 15, qd = lane >> 4;
    const int wm = (wave >> 1) * 64, wn = (wave & 1) * 64;

    f32x4 acc[4][4];
    const f32x4 z4 = {0.f, 0.f, 0.f, 0.f};
#pragma unroll
    for (int mi = 0; mi < 4; mi++)
#pragma unroll
        for (int ni = 0; ni < 4; ni++) acc[mi][ni] = z4;

    for (int k0 = 0; k0 < D_N; k0 += 32) {
#pragma unroll
        for (int c = t; c < 512; c += 256) {
            int row = c >> 2, cc = (c & 3) << 3;
            *(s16x8*)(As + row * 32 + cc) = *(const s16x8*)(hsp + (size_t)(m0 + row) * D_N + k0 + cc);
            *(s16x8*)(Bs + row * 32 + cc) = *(const s16x8*)(wto + (size_t)(n0 + row) * D_N + k0 + cc);
        }
        __syncthreads();
        s16x8 af[4], bfr[4];
#pragma unroll
        for (int mi = 0; mi < 4; mi++) af[mi]  = *(const s16x8*)(As + (wm + mi * 16 + ln) * 32 + qd * 8);
#pragma unroll
        for (int ni = 0; ni < 4; ni++) bfr[ni] = *(const s16x8*)(Bs + (wn + ni * 16 + ln) * 32 + qd * 8);
#pragma unroll
        for (int mi = 0; mi < 4; mi++)
#pragma unroll
            for (int ni = 0; ni < 4; ni++) acc[mi][ni] = mfma16(af[mi], bfr[ni], acc[mi][ni]);
        __syncthreads();
    }
#pragma unroll
    for (int ni = 0; ni < 4; ni++) {
        int n = n0 + wn + ni * 16 + ln;
        float bn = bo[n];
#pragma unroll
        for (int mi = 0; mi < 4; mi++) {
#pragma unroll
            for (int r = 0; r < 4; r++) {
                int m = m0 + wm + mi * 16 + qd * 4 + r;
                if (m >= M_ROWS) continue;
                int b = m >= S_N; int s = m - b * S_N;
                float v = acc[mi][ni][r] + bn;
                size_t off = (s >= TEXT_N)
                    ? ((size_t)(b * ST_N + (s - TEXT_N)) * D_N + n)
                    : ((size_t)2 * ST_N * D_N + (size_t)(b * TEXT_N + s) * D_N + n);
                out[off] = v;
            }
        }
    }
}

extern "C" void kernel_launch(void* const* d_in, const int* in_sizes, int n_in,
                              void* d_out, int out_size, void* d_ws, size_t ws_size,
                              hipStream_t stream) {
    const float* hid = (const float*)d_in[0];
    const float* enc = (const float*)d_in[1];
    const int*  mask = (const int*)d_in[2];
    const float* wq = (const float*)d_in[3];
    const float* bq = (const float*)d_in[4];
    const float* wk = (const float*)d_in[5];
    const float* bk = (const float*)d_in[6];
    const float* wv = (const float*)d_in[7];
    const float* bv = (const float*)d_in[8];
    const float* wo = (const float*)d_in[9];
    const float* bo = (const float*)d_in[10];

    bf16_t* w = (bf16_t*)d_ws;
    const size_t WSZ = (size_t)D_N * D_N;
    bf16_t* wtq = w;
    bf16_t* wtk = w + WSZ;
    bf16_t* wtv = w + 2 * WSZ;
    bf16_t* wto = w + 3 * WSZ;
    bf16_t* Qb  = w + 4 * WSZ;                                  // [2][16][1536][64]
    bf16_t* Kc  = Qb  + (size_t)2 * HEADS_N * SP_N * HD_N;      // [16][2752][64]
    bf16_t* Ku  = Kc  + (size_t)HEADS_N * L0P_N * HD_N;         // [16][1536][64]
    bf16_t* Vct = Ku  + (size_t)HEADS_N * SP_N * HD_N;          // [16][64][2752]
    bf16_t* Vut = Vct + (size_t)HEADS_N * HD_N * L0P_N;         // [16][64][1536]
    bf16_t* hsb = Vut + (size_t)HEADS_N * HD_N * SP_N;          // [3072][1024]

    transpose_k<<<dim3(32, 32, 4), dim3(32, 8), 0, stream>>>(wq, wk, wv, wo, wtq, wtk, wtv, wto);
    qkv_proj<<<dim3(8, 24, 3), 256, 0, stream>>>(enc, hid, wtq, wtk, wtv, bq, bk, bv,
                                                 Qb, Kc, Ku, Vct, Vut);
    attn_k<<<dim3(24, 16, 2), 256, 0, stream>>>(Qb, Kc, Ku, Vct, Vut, mask, hsb);
    out_proj<<<dim3(8, 24), 256, 0, stream>>>(hsb, wto, bo, (bf16_t*)d_out ? (float*)d_out : (float*)d_out);
}

// Round 3
// 226.077 us; speedup vs baseline: 1.4593x; 1.4593x over previous
//
#include <hip/hip_runtime.h>
#include <hip/hip_bf16.h>

#define TEXT_N 226
#define D_N    1024
#define HEADS_N 16
#define HD_N   64
#define ST_N   1248
#define S_N    1474        // TEXT+ST
#define L0_N   2722        // S+ST (cond key length)
#define NT_C   43          // cond j-tiles (64 each) -> 2752
#define NT_U   24          // uncond j-tiles        -> 1536
#define L0P_N  (NT_C*64)
#define SP_N   (NT_U*64)
#define M_ROWS 2948        // 2*S
#define MB_N   24          // m-blocks of 128 (3072 rows)
#define KB_N   16          // k-blocks of 64 (K=1024)
#define NEGB   -1000000000.0f

typedef __hip_bfloat16 bf16_t;
typedef short s16x8 __attribute__((ext_vector_type(8)));   // 8 bf16 (4 VGPRs)
typedef short s16x4 __attribute__((ext_vector_type(4)));   // 4 bf16
typedef float f32x4 __attribute__((ext_vector_type(4)));

__device__ __forceinline__ f32x4 mfma16(s16x8 a, s16x8 b, f32x4 c) {
    return __builtin_amdgcn_mfma_f32_16x16x32_bf16(a, b, c, 0, 0, 0);
}

typedef __attribute__((address_space(1))) const unsigned int gu32;
typedef __attribute__((address_space(3))) unsigned int lu32;
__device__ __forceinline__ void glds16(const void* g, void* l) {
    __builtin_amdgcn_global_load_lds((gu32*)g, (lu32*)l, 16, 0, 0);
}

__device__ __forceinline__ short f2bs(float x) {
    __hip_bfloat16 h = __float2bfloat16(x);
    return *(short*)&h;
}
// swizzled elem offset inside a [R][64] bf16 tile: 16B unit XORed by (row&7)
__device__ __forceinline__ int swz(int r, int c) {
    return r * 64 + ((((c >> 3) ^ (r & 7)) << 3) | (c & 7));
}

// ---------------- prep: weight-transpose images, x image, bias vectors ----------------
// wimg[4][8 nblk][16 kb][128][64]  (row=n, col=k, swizzled)
// xb  [24 mblk][16 kb][128][64]    (row=m, col=k, swizzled)
__global__ __launch_bounds__(256) void prep(
    const float* __restrict__ hid, const float* __restrict__ enc,
    const int* __restrict__ mask,
    const float* __restrict__ wq, const float* __restrict__ wk,
    const float* __restrict__ wv, const float* __restrict__ wo,
    bf16_t* __restrict__ wimg, bf16_t* __restrict__ xb,
    float* __restrict__ biasc, float* __restrict__ biasu) {
    __shared__ float Lw[64 * 129];
    const int b = blockIdx.x, t = threadIdx.x;
    if (b < 512) {                       // 4 weights x 8 nblk x 16 kb
        const int wid = b >> 7, nblk = (b >> 4) & 7, kb = b & 15;
        const float* w = (wid == 0) ? wq : (wid == 1) ? wk : (wid == 2) ? wv : wo;
        const int k0 = kb * 64, n0 = nblk * 128;
#pragma unroll
        for (int i = 0; i < 8; i++) {    // load w[k0..+64][n0..+128] into Lw[k][n]
            int idx = t + i * 256;       // 2048 float4 units
            int kr = idx >> 5, c4 = (idx & 31) * 4;
            float4 v = *(const float4*)(w + (size_t)(k0 + kr) * D_N + n0 + c4);
            Lw[kr * 129 + c4 + 0] = v.x; Lw[kr * 129 + c4 + 1] = v.y;
            Lw[kr * 129 + c4 + 2] = v.z; Lw[kr * 129 + c4 + 3] = v.w;
        }
        __syncthreads();
        bf16_t* dst = wimg + (((size_t)wid * 8 + nblk) * 16 + kb) * 8192;
#pragma unroll
        for (int i = 0; i < 4; i++) {    // 1024 output units
            int u = t + i * 256;
            int r = u >> 3, p = u & 7;   // r = n-row, p = physical unit
            int ul = p ^ (r & 7);        // logical k-unit stored here
            s16x8 o;
#pragma unroll
            for (int e = 0; e < 8; e++)
                o[e] = f2bs(Lw[(ul * 8 + e) * 129 + r]);
            *(s16x8*)(dst + r * 64 + p * 8) = o;
        }
    } else if (b < 896) {                // 384 x-tiles
        const int tile = b - 512;
        const int mblk = tile >> 4, kb = tile & 15;
        bf16_t* dst = xb + (size_t)tile * 8192;
#pragma unroll
        for (int i = 0; i < 4; i++) {
            int u = t + i * 256;
            int r = u >> 3, p = u & 7;
            int m = mblk * 128 + r;
            if (m >= M_ROWS) continue;   // padded rows stay poison (tiny, harmless)
            int bb = m >= S_N; int s = m - bb * S_N;
            const float* src = (s < TEXT_N)
                ? (enc + (size_t)(bb * TEXT_N + s) * D_N)
                : (hid + (size_t)(bb * ST_N + (s - TEXT_N)) * D_N);
            int k = kb * 64 + (p ^ (r & 7)) * 8;
            float4 f0 = *(const float4*)(src + k);
            float4 f1 = *(const float4*)(src + k + 4);
            s16x8 o;
            o[0]=f2bs(f0.x); o[1]=f2bs(f0.y); o[2]=f2bs(f0.z); o[3]=f2bs(f0.w);
            o[4]=f2bs(f1.x); o[5]=f2bs(f1.y); o[6]=f2bs(f1.z); o[7]=f2bs(f1.w);
            *(s16x8*)(dst + r * 64 + p * 8) = o;
        }
    } else {                             // bias vectors
        int j = (b - 896) * 256 + t;
        if (j < L0P_N) {
            float v = 0.f;
            if (j >= L0_N) v = NEGB;
            else if (j >= S_N) v = (mask[j - S_N] > 0) ? 0.f : NEGB;
            biasc[j] = v;
        }
        int j2 = j - L0P_N;
        if (j2 >= 0 && j2 < SP_N) biasu[j2] = (j2 < S_N) ? 0.f : NEGB;
    }
}

// ---------------- fused QKV projection GEMM (image inputs, glds staging) ----------------
__global__ __launch_bounds__(256) void qkv_proj(
    const bf16_t* __restrict__ xb, const bf16_t* __restrict__ wimg,
    const float* __restrict__ bq, const float* __restrict__ bk, const float* __restrict__ bv,
    bf16_t* __restrict__ Q, bf16_t* __restrict__ Kc, bf16_t* __restrict__ Ku,
    bf16_t* __restrict__ Vc, bf16_t* __restrict__ Vu) {
    __shared__ __align__(16) bf16_t As[8192];
    __shared__ __align__(16) bf16_t Bs[8192];
    const int z = blockIdx.z;
    const float* bias = (z == 0) ? bq : (z == 1) ? bk : bv;
    const int nblk = blockIdx.x, mblk = blockIdx.y;
    const int t = threadIdx.x, wave = t >> 6, lane = t & 63, ln = lane & 15, qd = lane >> 4;
    const int wm = (wave >> 1) * 64, wn = (wave & 1) * 64;
    const bf16_t* Ai = xb + (size_t)mblk * KB_N * 8192;
    const bf16_t* Bi = wimg + ((size_t)z * 8 + nblk) * KB_N * 8192;

    f32x4 acc[4][4];
    const f32x4 z4 = {0.f, 0.f, 0.f, 0.f};
#pragma unroll
    for (int mi = 0; mi < 4; mi++)
#pragma unroll
        for (int ni = 0; ni < 4; ni++) acc[mi][ni] = z4;

    for (int kb = 0; kb < KB_N; kb++) {
        const bf16_t* at = Ai + (size_t)kb * 8192;
        const bf16_t* bt = Bi + (size_t)kb * 8192;
#pragma unroll
        for (int i = 0; i < 4; i++) {
            glds16(at + (t + i * 256) * 8, As + (t + i * 256) * 8);
            glds16(bt + (t + i * 256) * 8, Bs + (t + i * 256) * 8);
        }
        __syncthreads();
#pragma unroll
        for (int kk = 0; kk < 2; kk++) {
            const int po = (((kk * 4 + qd) ^ (ln & 7)) << 3);
            s16x8 af[4], bfr[4];
#pragma unroll
            for (int mi = 0; mi < 4; mi++) af[mi]  = *(const s16x8*)(As + (wm + mi * 16 + ln) * 64 + po);
#pragma unroll
            for (int ni = 0; ni < 4; ni++) bfr[ni] = *(const s16x8*)(Bs + (wn + ni * 16 + ln) * 64 + po);
#pragma unroll
            for (int mi = 0; mi < 4; mi++)
#pragma unroll
                for (int ni = 0; ni < 4; ni++) acc[mi][ni] = mfma16(af[mi], bfr[ni], acc[mi][ni]);
        }
        __syncthreads();
    }

    // epilogue: scatter into attention layouts (K/V as swizzled tile images)
#pragma unroll
    for (int ni = 0; ni < 4; ni++) {
        int n = nblk * 128 + wn + ni * 16 + ln;
        float bn = bias[n];
        int h = n >> 6, d = n & 63;
#pragma unroll
        for (int mi = 0; mi < 4; mi++) {
#pragma unroll
            for (int r = 0; r < 4; r++) {
                int m = mblk * 128 + wm + mi * 16 + qd * 4 + r;
                if (m >= M_ROWS) continue;
                int b = m >= S_N; int s = m - b * S_N;
                bf16_t v = __float2bfloat16(acc[mi][ni][r] + bn);
                if (z == 0) {
                    Q[((size_t)(b * HEADS_N + h) * SP_N + s) * HD_N + d] = v;
                } else if (z == 1) {
                    if (!b) {
                        Kc[((size_t)h * NT_C + (s >> 6)) * 4096 + swz(s & 63, d)] = v;
                    } else {
                        Ku[((size_t)h * NT_U + (s >> 6)) * 4096 + swz(s & 63, d)] = v;
                        if (s >= TEXT_N) {
                            int j = S_N + s - TEXT_N;
                            Kc[((size_t)h * NT_C + (j >> 6)) * 4096 + swz(j & 63, d)] = v;
                        }
                    }
                } else {
                    if (!b) {
                        Vc[((size_t)h * NT_C + (s >> 6)) * 4096 + swz(d, s & 63)] = v;
                    } else {
                        Vu[((size_t)h * NT_U + (s >> 6)) * 4096 + swz(d, s & 63)] = v;
                        if (s >= TEXT_N) {
                            int j = S_N + s - TEXT_N;
                            Vc[((size_t)h * NT_C + (j >> 6)) * 4096 + swz(d, j & 63)] = v;
                        }
                    }
                }
            }
        }
    }
}

// ---------------- flash attention, S^T formulation ----------------
// grid (24 q-tiles, 16 heads, 2 cases); 4 waves x 16 q-rows; lane owns q = lane&15.
__global__ __launch_bounds__(256) void attn_k(
    const bf16_t* __restrict__ Q, const bf16_t* __restrict__ Kc, const bf16_t* __restrict__ Ku,
    const bf16_t* __restrict__ Vc, const bf16_t* __restrict__ Vu,
    const float* __restrict__ biasc, const float* __restrict__ biasu,
    bf16_t* __restrict__ hs) {
    __shared__ __align__(16) bf16_t Ks[4096];      // [j][d] swizzled
    __shared__ __align__(16) bf16_t Vs[4096];      // [d][j] swizzled
    __shared__ __align__(16) bf16_t Ps[4][1024];   // per-wave P [q][j] swizzled
    __shared__ __align__(16) float  bsL[L0P_N];
    const int cs = blockIdx.z, h = blockIdx.y, q0 = blockIdx.x * 64;
    const int nt = cs ? NT_U : NT_C;
    const bf16_t* Ki = cs ? (Ku + (size_t)h * NT_U * 4096) : (Kc + (size_t)h * NT_C * 4096);
    const bf16_t* Vi = cs ? (Vu + (size_t)h * NT_U * 4096) : (Vc + (size_t)h * NT_C * 4096);
    const float* bsrc = cs ? biasu : biasc;
    const int t = threadIdx.x, wave = t >> 6, lane = t & 63, ln = lane & 15, qd = lane >> 4;
    const int q = q0 + wave * 16 + ln;

    for (int i = t * 4; i < nt * 64; i += 1024)
        *(float4*)(bsL + i) = *(const float4*)(bsrc + i);

    const bf16_t* Qp = Q + ((size_t)(cs * HEADS_N + h) * SP_N + q) * HD_N;
    s16x8 qf[2];
    qf[0] = *(const s16x8*)(Qp + qd * 8);
    qf[1] = *(const s16x8*)(Qp + 32 + qd * 8);

    f32x4 o[4];
    const f32x4 z4 = {0.f, 0.f, 0.f, 0.f};
#pragma unroll
    for (int mi = 0; mi < 4; mi++) o[mi] = z4;
    float m_r = -1e30f, l_r = 0.f;
    bf16_t* pw = (bf16_t*)Ps[wave];

    for (int kt = 0; kt < nt; kt++) {
        const bf16_t* kp = Ki + (size_t)kt * 4096;
        const bf16_t* vp = Vi + (size_t)kt * 4096;
#pragma unroll
        for (int i = 0; i < 2; i++) {
            glds16(kp + (t + i * 256) * 8, Ks + (t + i * 256) * 8);
            glds16(vp + (t + i * 256) * 8, Vs + (t + i * 256) * 8);
        }
        __syncthreads();

        // S^T[j][q] = sum_d K[j][d] Q[q][d]
        f32x4 st[4];
#pragma unroll
        for (int ni = 0; ni < 4; ni++) st[ni] = z4;
#pragma unroll
        for (int kk = 0; kk < 2; kk++) {
            const int po = (((kk * 4 + qd) ^ (ln & 7)) << 3);
#pragma unroll
            for (int ni = 0; ni < 4; ni++) {
                s16x8 kf = *(const s16x8*)(Ks + (ni * 16 + ln) * 64 + po);
                st[ni] = mfma16(kf, qf[kk], st[ni]);
            }
        }
        // scale + bias (bias vector includes mask & OOB -1e9)
        float mloc = -1e30f;
#pragma unroll
        for (int ni = 0; ni < 4; ni++) {
            f32x4 bv4 = *(const f32x4*)(bsL + kt * 64 + ni * 16 + qd * 4);
#pragma unroll
            for (int r = 0; r < 4; r++) {
                st[ni][r] = st[ni][r] * 0.125f + bv4[r];
                mloc = fmaxf(mloc, st[ni][r]);
            }
        }
        mloc = fmaxf(mloc, __shfl_xor(mloc, 16));
        mloc = fmaxf(mloc, __shfl_xor(mloc, 32));
        float mn = fmaxf(m_r, mloc);
        float alpha = __expf(m_r - mn);
        m_r = mn;
        float rs = 0.f;
#pragma unroll
        for (int ni = 0; ni < 4; ni++)
#pragma unroll
            for (int r = 0; r < 4; r++) {
                float p = __expf(st[ni][r] - mn);
                st[ni][r] = p;
                rs += p;
            }
        rs += __shfl_xor(rs, 16);
        rs += __shfl_xor(rs, 32);
        l_r = l_r * alpha + rs;
        // P -> per-wave LDS (b64, swizzled, conflict-free)
#pragma unroll
        for (int ni = 0; ni < 4; ni++) {
            s16x4 pk;
            pk[0] = f2bs(st[ni][0]); pk[1] = f2bs(st[ni][1]);
            pk[2] = f2bs(st[ni][2]); pk[3] = f2bs(st[ni][3]);
            int c0 = ni * 16 + qd * 4;
            *(s16x4*)(pw + ln * 64 + ((((c0 >> 3) ^ (ln & 7)) << 3) | (c0 & 7))) = pk;
        }
#pragma unroll
        for (int mi = 0; mi < 4; mi++) {
            o[mi][0] *= alpha; o[mi][1] *= alpha; o[mi][2] *= alpha; o[mi][3] *= alpha;
        }
        asm volatile("s_waitcnt lgkmcnt(0)" ::: "memory");
        // O^T[d][q] += sum_j V^T[d][j] P[q][j]
#pragma unroll
        for (int kk = 0; kk < 2; kk++) {
            const int po = (((kk * 4 + qd) ^ (ln & 7)) << 3);
            s16x8 pb = *(const s16x8*)(pw + ln * 64 + po);
#pragma unroll
            for (int mi = 0; mi < 4; mi++) {
                s16x8 vf = *(const s16x8*)(Vs + (mi * 16 + ln) * 64 + po);
                o[mi] = mfma16(vf, pb, o[mi]);
            }
        }
        __syncthreads();
    }
    if (q < S_N) {
        float inv = 1.f / l_r;
        int m = cs * S_N + q;
        bf16_t* dst = hs + ((size_t)(m >> 7) * 16 + h) * 8192;
        int r = m & 127;
#pragma unroll
        for (int mi = 0; mi < 4; mi++) {
            s16x4 ov;
            ov[0] = f2bs(o[mi][0] * inv); ov[1] = f2bs(o[mi][1] * inv);
            ov[2] = f2bs(o[mi][2] * inv); ov[3] = f2bs(o[mi][3] * inv);
            int c0 = mi * 16 + qd * 4;
            *(s16x4*)(dst + r * 64 + ((((c0 >> 3) ^ (r & 7)) << 3) | (c0 & 7))) = ov;
        }
    }
}

// ---------------- output projection GEMM + split fp32 store ----------------
__global__ __launch_bounds__(256) void out_proj(
    const bf16_t* __restrict__ hsi, const bf16_t* __restrict__ wimg,
    const float* __restrict__ bo, float* __restrict__ out) {
    __shared__ __align__(16) bf16_t As[8192];
    __shared__ __align__(16) bf16_t Bs[8192];
    const int nblk = blockIdx.x, mblk = blockIdx.y;
    const int t = threadIdx.x, wave = t >> 6, lane = t & 63, ln = lane & 15, qd = lane >> 4;
    const int wm = (wave >> 1) * 64, wn = (wave & 1) * 64;
    const bf16_t* Ai = hsi + (size_t)mblk * KB_N * 8192;
    const bf16_t* Bi = wimg + ((size_t)3 * 8 + nblk) * KB_N * 8192;

    f32x4 acc[4][4];
    const f32x4 z4 = {0.f, 0.f, 0.f, 0.f};
#pragma unroll
    for (int mi = 0; mi < 4; mi++)
#pragma unroll
        for (int ni = 0; ni < 4; ni++) acc[mi][ni] = z4;

    for (int kb = 0; kb < KB_N; kb++) {
        const bf16_t* at = Ai + (size_t)kb * 8192;
        const bf16_t* bt = Bi + (size_t)kb * 8192;
#pragma unroll
        for (int i = 0; i < 4; i++) {
            glds16(at + (t + i * 256) * 8, As + (t + i * 256) * 8);
            glds16(bt + (t + i * 256) * 8, Bs + (t + i * 256) * 8);
        }
        __syncthreads();
#pragma unroll
        for (int kk = 0; kk < 2; kk++) {
            const int po = (((kk * 4 + qd) ^ (ln & 7)) << 3);
            s16x8 af[4], bfr[4];
#pragma unroll
            for (int mi = 0; mi < 4; mi++) af[mi]  = *(const s16x8*)(As + (wm + mi * 16 + ln) * 64 + po);
#pragma unroll
            for (int ni = 0; ni < 4; ni++) bfr[ni] = *(const s16x8*)(Bs + (wn + ni * 16 + ln) * 64 + po);
#pragma unroll
            for (int mi = 0; mi < 4; mi++)
#pragma unroll
                for (int ni = 0; ni < 4; ni++) acc[mi][ni] = mfma16(af[mi], bfr[ni], acc[mi][ni]);
        }
        __syncthreads();
    }
#pragma unroll
    for (int ni = 0; ni < 4; ni++) {
        int n = nblk * 128 + wn + ni * 16 + ln;
        float bn = bo[n];
#pragma unroll
        for (int mi = 0; mi < 4; mi++) {
#pragma unroll
            for (int r = 0; r < 4; r++) {
                int m = mblk * 128 + wm + mi * 16 + qd * 4 + r;
                if (m >= M_ROWS) continue;
                int b = m >= S_N; int s = m - b * S_N;
                float v = acc[mi][ni][r] + bn;
                size_t off = (s >= TEXT_N)
                    ? ((size_t)(b * ST_N + (s - TEXT_N)) * D_N + n)
                    : ((size_t)2 * ST_N * D_N + (size_t)(b * TEXT_N + s) * D_N + n);
                out[off] = v;
            }
        }
    }
}

extern "C" void kernel_launch(void* const* d_in, const int* in_sizes, int n_in,
                              void* d_out, int out_size, void* d_ws, size_t ws_size,
                              hipStream_t stream) {
    const float* hid = (const float*)d_in[0];
    const float* enc = (const float*)d_in[1];
    const int*  mask = (const int*)d_in[2];
    const float* wq = (const float*)d_in[3];
    const float* bq = (const float*)d_in[4];
    const float* wk = (const float*)d_in[5];
    const float* bk = (const float*)d_in[6];
    const float* wv = (const float*)d_in[7];
    const float* bv = (const float*)d_in[8];
    const float* wo = (const float*)d_in[9];
    const float* bo = (const float*)d_in[10];

    bf16_t* w = (bf16_t*)d_ws;
    const size_t WIMG = (size_t)4 * 8 * 16 * 8192;       // 4,194,304
    const size_t XIMG = (size_t)MB_N * KB_N * 8192;      // 3,145,728
    bf16_t* wimg = w;
    bf16_t* xb   = wimg + WIMG;
    bf16_t* Qb   = xb + XIMG;                            // [2][16][1536][64]
    bf16_t* Kc   = Qb + (size_t)2 * HEADS_N * SP_N * HD_N;
    bf16_t* Ku   = Kc + (size_t)HEADS_N * NT_C * 4096;
    bf16_t* Vc   = Ku + (size_t)HEADS_N * NT_U * 4096;
    bf16_t* Vu   = Vc + (size_t)HEADS_N * NT_C * 4096;
    float*  biasf = (float*)(Vu + (size_t)HEADS_N * NT_U * 4096);
    float*  biasc = biasf;
    float*  biasu = biasf + L0P_N;
    bf16_t* hsi  = xb;   // reuse x-image region for hs image (xb dead after qkv_proj)

    prep<<<913, 256, 0, stream>>>(hid, enc, mask, wq, wk, wv, wo, wimg, xb, biasc, biasu);
    qkv_proj<<<dim3(8, MB_N, 3), 256, 0, stream>>>(xb, wimg, bq, bk, bv, Qb, Kc, Ku, Vc, Vu);
    attn_k<<<dim3(24, 16, 2), 256, 0, stream>>>(Qb, Kc, Ku, Vc, Vu, biasc, biasu, hsi);
    out_proj<<<dim3(8, MB_N), 256, 0, stream>>>(hsi, wimg, bo, (float*)d_out);
}